// Round 13
// baseline (563.879 us; speedup 1.0000x reference)
//
#include <hip/hip_runtime.h>
#include <math.h>

#define B_    8
#define N_TOK 3136
#define C_    384
#define DH    48
#define NK    784
#define HID   768
#define M1    25088
#define M2    6272
#define M1Q   6272      // quarter of M1

typedef unsigned short u16;
typedef __attribute__((ext_vector_type(8))) short bf16x8;
typedef __attribute__((ext_vector_type(4))) float f32x4;

__device__ __forceinline__ float b2f(u16 u) {
  return __uint_as_float(((unsigned)u) << 16);
}
__device__ __forceinline__ u16 f2b(float f) {
  unsigned u = __float_as_uint(f);
  return (u16)((u + 0x7fffu + ((u >> 16) & 1u)) >> 16);  // RNE
}
__device__ __forceinline__ u16 f2b_trunc(float f) {
  return (u16)(__float_as_uint(f) >> 16);
}
__device__ __forceinline__ void gload_lds16(const u16* g, u16* l) {
  __builtin_amdgcn_global_load_lds(
      (const __attribute__((address_space(1))) void*)g,
      (__attribute__((address_space(3))) void*)l, 16, 0, 0);
}

// -------- Fused pre-pass: 6 weight transposes + LN1 + pool, one launch --------
struct PreArgs {
  const float* src[6];
  u16* dst[6];
  int K[6], N[6];
  const float* x;
  const float* w;
  const float* b;
  u16* Y;
  u16* KV;
};
__global__ __launch_bounds__(256) void pre_kernel(PreArgs pa) {
  __shared__ u16 tile[64][73];
  const int bid = blockIdx.x;
  if (bid < 288) {
    int id, bx, by;
    if (bid < 144)      { id = bid / 36; int j = bid % 36;  bx = j % 6;  by = j / 6; }
    else if (bid < 216) { id = 4;        int j = bid - 144; bx = j % 12; by = j / 12; }
    else                { id = 5;        int j = bid - 216; bx = j % 6;  by = j / 6; }
    const float* W = pa.src[id];
    u16* WT = pa.dst[id];
    const int K = pa.K[id], N = pa.N[id];
    const int k0 = by * 64, n0 = bx * 64;
    for (int i = threadIdx.x; i < 64 * 64; i += 256) {
      int kk = i >> 6, nn = i & 63;
      tile[kk][nn] = f2b(W[(size_t)(k0 + kk) * N + n0 + nn]);
    }
    __syncthreads();
    for (int i = threadIdx.x; i < 64 * 64; i += 256) {
      int nn = i >> 6, kk = i & 63;
      WT[(size_t)(n0 + nn) * K + k0 + kk] = tile[kk][nn];
    }
  } else if (bid < 288 + M1 / 4) {
    const int row = (bid - 288) * 4 + (threadIdx.x >> 6);
    const int lane = threadIdx.x & 63;
    const size_t base = (size_t)row * C_;
    float v[6];
#pragma unroll
    for (int i = 0; i < 6; ++i) v[i] = pa.x[base + lane + 64 * i];
    float s = 0.f;
#pragma unroll
    for (int i = 0; i < 6; ++i) s += v[i];
#pragma unroll
    for (int off = 32; off > 0; off >>= 1) s += __shfl_xor(s, off);
    const float mu = s * (1.0f / C_);
    float q = 0.f;
#pragma unroll
    for (int i = 0; i < 6; ++i) { float d = v[i] - mu; q += d * d; }
#pragma unroll
    for (int off = 32; off > 0; off >>= 1) q += __shfl_xor(q, off);
    const float r = rsqrtf(q * (1.0f / C_) + 1e-6f);
#pragma unroll
    for (int i = 0; i < 6; ++i) {
      int c = lane + 64 * i;
      pa.Y[base + c] = f2b((v[i] - mu) * r * pa.w[c] + pa.b[c]);
    }
  } else {
    int t = (bid - 288 - M1 / 4) * 256 + threadIdx.x;
    int c = t % C_;
    int row = t / C_;
    int bb = row / NK;
    int rr = row - bb * NK;
    int hk = rr / 28;
    int wk = rr - hk * 28;
    const float* p = pa.x + ((size_t)(bb * N_TOK + hk * 112 + wk * 2)) * C_ + c;
    pa.KV[t] = f2b(0.25f * (p[0] + p[C_] + p[56 * C_] + p[57 * C_]));
  }
}

// ------------- LayerNorm bf16 -> bf16 (4 rows/block) -------------
__global__ __launch_bounds__(256) void ln2_rows(const u16* __restrict__ X,
    const float* __restrict__ w, const float* __restrict__ b, u16* __restrict__ Y) {
  const int row = blockIdx.x * 4 + (threadIdx.x >> 6);
  const int lane = threadIdx.x & 63;
  const size_t base = (size_t)row * C_;
  float v[6];
#pragma unroll
  for (int i = 0; i < 6; ++i) v[i] = b2f(X[base + lane + 64 * i]);
  float s = 0.f;
#pragma unroll
  for (int i = 0; i < 6; ++i) s += v[i];
#pragma unroll
  for (int off = 32; off > 0; off >>= 1) s += __shfl_xor(s, off);
  const float mu = s * (1.0f / C_);
  float q = 0.f;
#pragma unroll
  for (int i = 0; i < 6; ++i) { float d = v[i] - mu; q += d * d; }
#pragma unroll
  for (int off = 32; off > 0; off >>= 1) q += __shfl_xor(q, off);
  const float r = rsqrtf(q * (1.0f / C_) + 1e-6f);
#pragma unroll
  for (int i = 0; i < 6; ++i) {
    int c = lane + 64 * i;
    Y[base + c] = f2b((v[i] - mu) * r * w[c] + b[c]);
  }
}

// ------- MFMA GEMM core: 256x128 block tile, 4 waves (2x2, wave = 128x64) ------
// Per K-iter per wave: 12 b128 LDS reads feed 32 MFMAs (vs 8:16 before).
// Partial M tiles: stores (and residual reads) guarded by row < M.
template<int EPI, bool RES32, bool OUT32>
__device__ __forceinline__ void gemm_core(
    const u16* __restrict__ A, const u16* __restrict__ BT,
    const float* __restrict__ bias, const void* __restrict__ resv,
    void* __restrict__ Cv, int M, int N, int K, int m0, int n0) {
  __shared__ u16 As[256 * 64];
  __shared__ u16 Bs[128 * 64];
  const int tid  = threadIdx.x;
  const int wave = tid >> 6;
  const int lane = tid & 63;
  const int quad = lane >> 4;
  const int ll   = lane & 15;
  const int wm   = wave >> 1, wn = wave & 1;
  const int lr8  = lane >> 3;
  const int sg   = lane & 7;

  f32x4 acc[8][4];
#pragma unroll
  for (int i = 0; i < 8; ++i)
#pragma unroll
    for (int j = 0; j < 4; ++j) acc[i][j] = (f32x4){0.f, 0.f, 0.f, 0.f};

  for (int kk0 = 0; kk0 < K; kk0 += 64) {
    __syncthreads();
    // A: wave stages rows [wave*64, wave*64+64).
#pragma unroll
    for (int c = 0; c < 8; ++c) {
      const int r = wave * 64 + c * 8 + lr8;
      const int g = sg ^ (r & 7);
      gload_lds16(A + (size_t)(m0 + r) * K + kk0 + g * 8,
                  As + (size_t)(wave * 64 + c * 8) * 64);
    }
    // B: wave stages rows [wave*32, wave*32+32).
#pragma unroll
    for (int c = 0; c < 4; ++c) {
      const int r = wave * 32 + c * 8 + lr8;
      const int g = sg ^ (r & 7);
      gload_lds16(BT + (size_t)(n0 + r) * K + kk0 + g * 8,
                  Bs + (size_t)(wave * 32 + c * 8) * 64);
    }
    __syncthreads();
#pragma unroll
    for (int ks = 0; ks < 2; ++ks) {
      const int gsw = (quad + 4 * ks) ^ (ll & 7);
      bf16x8 af[8], bfr[4];
#pragma unroll
      for (int im = 0; im < 8; ++im)
        af[im] = *(const bf16x8*)&As[(size_t)(wm * 128 + im * 16 + ll) * 64 + gsw * 8];
#pragma unroll
      for (int jn = 0; jn < 4; ++jn)
        bfr[jn] = *(const bf16x8*)&Bs[(size_t)(wn * 64 + jn * 16 + ll) * 64 + gsw * 8];
#pragma unroll
      for (int im = 0; im < 8; ++im)
#pragma unroll
        for (int jn = 0; jn < 4; ++jn)
          acc[im][jn] = __builtin_amdgcn_mfma_f32_16x16x32_bf16(
              af[im], bfr[jn], acc[im][jn], 0, 0, 0);
    }
  }

  float bb[4];
#pragma unroll
  for (int jn = 0; jn < 4; ++jn) bb[jn] = bias[n0 + wn * 64 + jn * 16 + ll];
#pragma unroll
  for (int im = 0; im < 8; ++im) {
    const int row = m0 + wm * 128 + im * 16 + quad * 4;
#pragma unroll
    for (int jn = 0; jn < 4; ++jn) {
      const int col = n0 + wn * 64 + jn * 16 + ll;
#pragma unroll
      for (int r = 0; r < 4; ++r) {
        if (row + r >= M) continue;
        float o = acc[im][jn][r] + bb[jn];
        if (EPI == 1) {
          o = 0.5f * o * (1.0f + erff(o * 0.70710678118654752f));
        } else if (EPI == 2) {
          size_t ri = (size_t)(row + r) * N + col;
          o += RES32 ? ((const float*)resv)[ri] : b2f(((const u16*)resv)[ri]);
        }
        if (OUT32) ((float*)Cv)[(size_t)(row + r) * N + col] = o;
        else       ((u16*)Cv)[(size_t)(row + r) * N + col] = f2b(o);
      }
    }
  }
}

template<int EPI, bool RES32, bool OUT32>
__global__ __launch_bounds__(256) void gemm_bt(
    const u16* __restrict__ A, const u16* __restrict__ BT,
    const float* __restrict__ bias, const void* __restrict__ resv,
    void* __restrict__ Cv, int M, int N, int K) {
  gemm_core<EPI, RES32, OUT32>(A, BT, bias, resv, Cv, M, N, K,
                               blockIdx.y << 8, blockIdx.x << 7);
}

// Q/K/V fused: z selects {Q, K, V}; K/V blocks beyond M2 exit early.
struct QKVArgs {
  const u16* A[3];
  const u16* BT[3];
  const float* bias[3];
  u16* C[3];
  int M[3];
};
__global__ __launch_bounds__(256) void gemm_qkv(QKVArgs a) {
  const int z = blockIdx.z;
  const int m0 = blockIdx.y << 8;
  if (m0 >= a.M[z]) return;
  gemm_core<0, false, false>(a.A[z], a.BT[z], a.bias[z], nullptr, a.C[z],
                             a.M[z], C_, C_, m0, blockIdx.x << 7);
}

// ---------------- MFMA flash attention: Q fragments in registers ----------------
// 128 q-rows, 8 waves, 64-key tiles. Q is loaded once into per-lane registers
// (reused across all 13 tiles) -> Qs LDS eliminated (53 -> 34.6 KB, 4 blk/CU).
#define QS_STR 72
__global__ __launch_bounds__(512) void attn_mfma(
    const u16* __restrict__ Q, const u16* __restrict__ Kb,
    const u16* __restrict__ Vb, u16* __restrict__ O) {
  __shared__ u16 Ks[64 * QS_STR];
  __shared__ u16 Vt[48 * QS_STR];        // Vt[d][key]
  __shared__ u16 Ps[128 * QS_STR];       // per-wave 16-row bands
  const int tid  = threadIdx.x;
  const int wave = tid >> 6;             // 0..7
  const int lane = tid & 63;
  const int quad = lane >> 4;
  const int ll   = lane & 15;
  const int qt   = blockIdx.x;           // 0..24
  const int bh   = blockIdx.y;
  const int b    = bh >> 3, h = bh & 7;
  const int q0   = qt * 128;
  const float scale = 0.14433756729740643f;  // 48^-0.5

  // Zero pad cols 48..63 of Ks once.
  for (int i = tid; i < 64 * 16; i += 512) {
    int r = i >> 4, c = i & 15;
    Ks[r * QS_STR + 48 + c] = 0;
  }
  // Load this lane's Q fragments (pre-scaled) into registers.
  // A-layout: row = wave*16 + ll, k = k0 + quad*8 (+j). k0=32 frag is zero for
  // quad>=2 (k >= 48 pad).
  bf16x8 aq0 = {0,0,0,0,0,0,0,0}, aq1 = {0,0,0,0,0,0,0,0};
  {
    const int qrow = q0 + wave * 16 + ll;
    if (qrow < N_TOK) {
      const u16* qp = Q + ((size_t)b * N_TOK + qrow) * C_ + h * DH;
      uint4 v0 = *(const uint4*)(qp + quad * 8);
      const u16* vp = (const u16*)&v0;
      u16 ov[8];
#pragma unroll
      for (int j = 0; j < 8; ++j) ov[j] = f2b(b2f(vp[j]) * scale);
      aq0 = *(const bf16x8*)ov;
      if (quad < 2) {
        uint4 v1 = *(const uint4*)(qp + 32 + quad * 8);
        const u16* wp = (const u16*)&v1;
#pragma unroll
        for (int j = 0; j < 8; ++j) ov[j] = f2b(b2f(wp[j]) * scale);
        aq1 = *(const bf16x8*)ov;
      }
    }
  }

  f32x4 Ofr[3] = {{0.f,0.f,0.f,0.f},{0.f,0.f,0.f,0.f},{0.f,0.f,0.f,0.f}};
  float lrow[4] = {0.f, 0.f, 0.f, 0.f};

  for (int t = 0; t < 13; ++t) {
    const int kbase = t * 64;
    __syncthreads();   // prev-tile LDS reads done before restage
    // Stage K: key = tid/8 (0..63), part = tid%8 (<6).
    {
      const int key = tid >> 3, part = tid & 7;
      if (part < 6 && kbase + key < NK) {
        uint4 v = *(const uint4*)(Kb + ((size_t)(b * NK) + kbase + key) * C_ + h * DH + part * 8);
        *(uint4*)&Ks[key * QS_STR + part * 8] = v;
      }
    }
    // Stage V transposed: part = tid/64 (<6), key = tid%64.
    {
      const int part = tid >> 6, key = tid & 63;
      if (part < 6 && kbase + key < NK) {
        uint4 v = *(const uint4*)(Vb + ((size_t)(b * NK) + kbase + key) * C_ + h * DH + part * 8);
        const u16* vp = (const u16*)&v;
#pragma unroll
        for (int j = 0; j < 8; ++j)
          Vt[(part * 8 + j) * QS_STR + key] = vp[j];
      }
    }
    __syncthreads();

    // S = Q @ K^T : 4 key-subtiles x 2 k-steps (A from registers).
    f32x4 S[4];
#pragma unroll
    for (int nt = 0; nt < 4; ++nt) {
      f32x4 acc = {0.f, 0.f, 0.f, 0.f};
      bf16x8 b0 = *(const bf16x8*)&Ks[(nt * 16 + ll) * QS_STR + quad * 8];
      acc = __builtin_amdgcn_mfma_f32_16x16x32_bf16(aq0, b0, acc, 0, 0, 0);
      bf16x8 b1 = *(const bf16x8*)&Ks[(nt * 16 + ll) * QS_STR + 32 + quad * 8];
      acc = __builtin_amdgcn_mfma_f32_16x16x32_bf16(aq1, b1, acc, 0, 0, 0);
      if (kbase + nt * 16 + ll >= NK)
        acc = (f32x4){-1e30f, -1e30f, -1e30f, -1e30f};
      S[nt] = acc;
    }
    // p = exp(s); accumulate per-lane partial l; pack P (XOR swizzle on quad).
#pragma unroll
    for (int nt = 0; nt < 4; ++nt) {
      const int g = nt * 2 + (ll >> 3);
      const int gp = g ^ quad;
#pragma unroll
      for (int r = 0; r < 4; ++r) {
        float p = __expf(S[nt][r]);
        lrow[r] += p;
        Ps[(wave * 16 + quad * 4 + r) * QS_STR + (gp << 3) + (ll & 7)] = f2b_trunc(p);
      }
    }
    // O += P @ V.
#pragma unroll
    for (int dt = 0; dt < 3; ++dt)
#pragma unroll
      for (int ks = 0; ks < 2; ++ks) {
        const int gp = ((ks << 2) + quad) ^ ((ll >> 2) & 3);
        bf16x8 a = *(const bf16x8*)&Ps[(wave * 16 + ll) * QS_STR + (gp << 3)];
        bf16x8 bb = *(const bf16x8*)&Vt[(dt * 16 + ll) * QS_STR + ks * 32 + quad * 8];
        Ofr[dt] = __builtin_amdgcn_mfma_f32_16x16x32_bf16(a, bb, Ofr[dt], 0, 0, 0);
      }
  }
#pragma unroll
  for (int msk = 1; msk < 16; msk <<= 1)
#pragma unroll
    for (int r = 0; r < 4; ++r)
      lrow[r] += __shfl_xor(lrow[r], msk);
  float inv[4];
#pragma unroll
  for (int r = 0; r < 4; ++r) inv[r] = 1.0f / lrow[r];
#pragma unroll
  for (int dt = 0; dt < 3; ++dt)
#pragma unroll
    for (int r = 0; r < 4; ++r) {
      int qrow = q0 + wave * 16 + quad * 4 + r;
      if (qrow < N_TOK)
        O[((size_t)b * N_TOK + qrow) * C_ + h * DH + dt * 16 + ll] =
            f2b(Ofr[dt][r] * inv[r]);
    }
}

// ---------------- Diagnostics ----------------
__global__ __launch_bounds__(256) void marker_fill(
    float* __restrict__ out, size_t n, float val) {
  size_t i = (size_t)blockIdx.x * 256 + threadIdx.x;
  const size_t stride = (size_t)gridDim.x * 256;
  for (; i < n; i += stride) out[i] = 0.f;
  if (blockIdx.x == 0 && threadIdx.x == 0) out[0] = val;
}

// ---------------- launch ----------------
extern "C" void kernel_launch(void* const* d_in, const int* in_sizes, int n_in,
                              void* d_out, int out_size, void* d_ws, size_t ws_size,
                              hipStream_t stream) {
  const float* x    = (const float*)d_in[0];
  const float* ln1w = (const float*)d_in[1];
  const float* ln1b = (const float*)d_in[2];
  const float* qw   = (const float*)d_in[3];
  const float* qb   = (const float*)d_in[4];
  const float* kw   = (const float*)d_in[5];
  const float* kb   = (const float*)d_in[6];
  const float* vw   = (const float*)d_in[7];
  const float* vb   = (const float*)d_in[8];
  const float* pw   = (const float*)d_in[9];
  const float* pb   = (const float*)d_in[10];
  const float* ln2w = (const float*)d_in[11];
  const float* ln2b = (const float*)d_in[12];
  const float* fc1w = (const float*)d_in[13];
  const float* fc1b = (const float*)d_in[14];
  const float* fc2w = (const float*)d_in[15];
  const float* fc2b = (const float*)d_in[16];

  const size_t BUF = (size_t)M1 * C_;
  float* outf = (float*)d_out;

  {
    static const int exp_sizes[19] = {
      M1 * C_, C_, C_, C_ * C_, C_, C_ * C_, C_, C_ * C_, C_, C_ * C_, C_,
      C_, C_, C_ * HID, HID, HID * C_, C_, 1, 1};
    int bad = -1;
    if (n_in != 19) bad = 99;
    else {
      for (int i = 0; i < 19; ++i)
        if (in_sizes[i] != exp_sizes[i]) { bad = i; break; }
    }
    if (bad >= 0) {
      marker_fill<<<1024, 256, 0, stream>>>(outf, BUF, 10000.0f + (float)bad);
      return;
    }
  }
  const size_t need_min  = 4096 + 3 * BUF * sizeof(u16);                      // 57.8 MB
  const size_t need_full = 4096 + (3 * BUF + (size_t)M1 * HID) * sizeof(u16); // 96.4 MB
  if (ws_size < need_min) {
    marker_fill<<<1024, 256, 0, stream>>>(outf, BUF, 30000.0f + (float)(ws_size >> 20));
    return;
  }
  const bool full_mlp = (ws_size >= need_full);

  u16* T0 = (u16*)((char*)d_ws + 4096);
  u16* T1 = T0 + BUF;
  u16* U  = T1 + BUF;
  u16* P  = U;
  u16* KB = U + (size_t)M2 * C_;
  u16* VB = U + (size_t)2 * M2 * C_;
  u16* HBq = U;
  u16* HBfull = U + BUF;
  u16* WTb = U + BUF - (size_t)(4 * C_ * C_ + 2 * C_ * HID);
  u16* wtq = WTb;
  u16* wtk = wtq + C_ * C_;
  u16* wtv = wtk + C_ * C_;
  u16* wtp = wtv + C_ * C_;
  u16* wtf1 = wtp + C_ * C_;
  u16* wtf2 = wtf1 + (size_t)C_ * HID;

  // 1. Fused pre-pass: weight transposes + LN1 + pool.
  {
    PreArgs pa;
    pa.src[0] = qw;   pa.dst[0] = wtq;  pa.K[0] = C_;  pa.N[0] = C_;
    pa.src[1] = kw;   pa.dst[1] = wtk;  pa.K[1] = C_;  pa.N[1] = C_;
    pa.src[2] = vw;   pa.dst[2] = wtv;  pa.K[2] = C_;  pa.N[2] = C_;
    pa.src[3] = pw;   pa.dst[3] = wtp;  pa.K[3] = C_;  pa.N[3] = C_;
    pa.src[4] = fc1w; pa.dst[4] = wtf1; pa.K[4] = C_;  pa.N[4] = HID;
    pa.src[5] = fc2w; pa.dst[5] = wtf2; pa.K[5] = HID; pa.N[5] = C_;
    pa.x = x; pa.w = ln1w; pa.b = ln1b; pa.Y = T0; pa.KV = P;
    pre_kernel<<<288 + M1 / 4 + (M2 * C_) / 256, 256, 0, stream>>>(pa);
  }

  // 2. Q/K/V projections in one launch (256-row tiles).
  {
    QKVArgs qa;
    qa.A[0] = T0; qa.BT[0] = wtq; qa.bias[0] = qb; qa.C[0] = T1; qa.M[0] = M1;
    qa.A[1] = P;  qa.BT[1] = wtk; qa.bias[1] = kb; qa.C[1] = KB; qa.M[1] = M2;
    qa.A[2] = P;  qa.BT[2] = wtv; qa.bias[2] = vb; qa.C[2] = VB; qa.M[2] = M2;
    gemm_qkv<<<dim3(3, 98, 3), 256, 0, stream>>>(qa);
  }

  // 3. MFMA flash attention -> T0
  attn_mfma<<<dim3(25, 64), 512, 0, stream>>>(T1, KB, VB, T0);

  // 4. x1 = x(f32) + T0 @ pw + pb -> T1 (bf16)
  gemm_bt<2, true, false><<<dim3(3, 98), 256, 0, stream>>>(
      T0, wtp, pb, x, T1, M1, C_, C_);

  // 5. LN2(T1) -> T0
  ln2_rows<<<M1 / 4, 256, 0, stream>>>(T1, ln2w, ln2b, T0);

  // 6/7. MLP.
  if (full_mlp) {
    gemm_bt<1, false, false><<<dim3(6, 98), 256, 0, stream>>>(
        T0, wtf1, fc1b, nullptr, HBfull, M1, HID, C_);
    gemm_bt<2, false, true><<<dim3(3, 98), 256, 0, stream>>>(
        HBfull, wtf2, fc2b, T1, outf, M1, C_, HID);
  } else {
    for (int qtr = 0; qtr < 4; ++qtr) {
      const size_t ro = (size_t)qtr * M1Q;
      gemm_bt<1, false, false><<<dim3(6, 25), 256, 0, stream>>>(
          T0 + ro * C_, wtf1, fc1b, nullptr, HBq, M1Q, HID, C_);
      gemm_bt<2, false, true><<<dim3(3, 25), 256, 0, stream>>>(
          HBq, wtf2, fc2b, T1 + ro * C_, outf + ro * C_, M1Q, C_, HID);
    }
  }
}